// Round 17
// baseline (61.291 us; speedup 1.0000x reference)
//
#include <hip/hip_runtime.h>

#define D      128
#define NT     256
#define KB     320       // bin blocks (edge partition)
#define CAPBB  64        // records per (block,bin) cell
#define NBMAX  256       // max bins => n_nodes <= 65536

typedef __attribute__((ext_vector_type(4))) _Float16 half4;
typedef __attribute__((ext_vector_type(8))) _Float16 half8;
typedef __attribute__((ext_vector_type(4))) float    f32x4;

__device__ __forceinline__ float4 elu_mul(float4 g, float4 w) {
    float4 v;
    v.x = g.x * w.x; v.y = g.y * w.y; v.z = g.z * w.z; v.w = g.w * w.w;
    v.x = (v.x > 0.0f) ? v.x : (__expf(v.x) - 1.0f);
    v.y = (v.y > 0.0f) ? v.y : (__expf(v.y) - 1.0f);
    v.z = (v.z > 0.0f) ? v.z : (__expf(v.z) - 1.0f);
    v.w = (v.w > 0.0f) ? v.w : (__expf(v.w) - 1.0f);
    return v;
}

// ---------------------------------------------------------------------------
// K1 (fused): blocks [0,KB): deterministic binning into private (blk,bin)
// cells — LDS rank only, no global atomics, no init. Blocks [KB,...): emb.
// ---------------------------------------------------------------------------
__global__ __launch_bounds__(NT)
void fused_kernel(const float* __restrict__ ge, const float* __restrict__ weight,
                  const int* __restrict__ e_feat, const int* __restrict__ src,
                  const int* __restrict__ dst,
                  _Float16* __restrict__ emb, uint2* __restrict__ binned,
                  int* __restrict__ cnts, uint2* __restrict__ spill,
                  int* __restrict__ spill_cnt,
                  int n_nodes, int n_edges, int nbins, int per_block) {
    if ((int)blockIdx.x < KB) {
        __shared__ int rk[NBMAX];
        __shared__ int sp;
        int t = threadIdx.x;
        for (int i = t; i < NBMAX; i += NT) rk[i] = 0;
        if (t == 0) sp = 0;
        __syncthreads();

        int blk = blockIdx.x;
        int e0 = blk * per_block;
        int e1 = e0 + per_block; if (e1 > n_edges) e1 = n_edges;
        for (int e = e0 + t; e < e1; e += NT) {
            int d = dst[e];
            int b = d >> 8;
            int f = e_feat[e];
            unsigned int flag = (f == 0 || f == 6 || f == 14 || f == 30) ? 1u : 0u;
            unsigned int rec  = (unsigned int)src[e] | (flag << 31);
            int r = atomicAdd(&rk[b], 1);
            if (r < CAPBB) {
                binned[((size_t)blk * nbins + b) * CAPBB + r] =
                    make_uint2(rec, (unsigned int)(d & 255));
            } else {
                int s = atomicAdd(&sp, 1);
                spill[(size_t)blk * per_block + s] = make_uint2(rec, (unsigned int)d);
            }
        }
        __syncthreads();
        for (int b = t; b < nbins; b += NT)
            cnts[blk * nbins + b] = rk[b] < CAPBB ? rk[b] : CAPBB;
        if (t == 0) spill_cnt[blk] = sp;
    } else {
        int t = ((int)blockIdx.x - KB) * NT + threadIdx.x;
        int quads = n_nodes * (D / 4);
        if (t < quads) {
            int col = (t & 31) * 4;
            float4 g = *reinterpret_cast<const float4*>(ge + (size_t)t * 4);
            float4 w = *reinterpret_cast<const float4*>(weight + col);
            float4 v = elu_mul(g, w);
            half4 h;
            h.x = (_Float16)v.x; h.y = (_Float16)v.y;
            h.z = (_Float16)v.z; h.w = (_Float16)v.w;
            *reinterpret_cast<half4*>(emb + (size_t)t * 4) = h;
        }
    }
}

// ---------------------------------------------------------------------------
// K2: per-bin CSR pack, phases parallelized over all 1024 threads via
// padded-slot striding (KB*CAPBB slots, independent loads).
// ---------------------------------------------------------------------------
__global__ __launch_bounds__(1024)
void csr_kernel(const uint2* __restrict__ binned, const int* __restrict__ cnts,
                uint2* __restrict__ offdeg, unsigned int* __restrict__ bucket,
                const int* __restrict__ spill_cnt, int* __restrict__ spill_total,
                int n_nodes, int nbins, int capb_out) {
    __shared__ int cnt2[NBMAX];
    __shared__ int off2[NBMAX];
    __shared__ int rk2[NBMAX];
    __shared__ int cellc[KB];
    __shared__ int stot;
    int t = threadIdx.x;
    int b = blockIdx.x;

    for (int i = t; i < NBMAX; i += 1024) { cnt2[i] = 0; rk2[i] = 0; }
    if (t < KB) cellc[t] = cnts[t * nbins + b];
    if (t == 0) stot = 0;
    __syncthreads();

    const int nslots = KB * CAPBB;

    // phase A: node-local histogram (independent strided loads)
    for (int slot = t; slot < nslots; slot += 1024) {
        int cell = slot >> 6;           // CAPBB = 64
        int j    = slot & (CAPBB - 1);
        if (j < cellc[cell]) {
            uint2 r = binned[((size_t)cell * nbins + b) * CAPBB + j];
            atomicAdd(&cnt2[r.y], 1);
        }
    }
    __syncthreads();

    // inclusive scan over 256 node slots
    if (t < NBMAX) off2[t] = cnt2[t];
    __syncthreads();
    for (int d2 = 1; d2 < NBMAX; d2 <<= 1) {
        int x = 0;
        if (t < NBMAX && t >= d2) x = off2[t - d2];
        __syncthreads();
        if (t < NBMAX) off2[t] += x;
        __syncthreads();
    }

    int G = b * capb_out;
    if (t < NBMAX) {
        int node = (b << 8) + t;
        if (node < n_nodes)
            offdeg[node] = make_uint2((unsigned int)(G + off2[t] - cnt2[t]),
                                      (unsigned int)cnt2[t]);
    }
    __syncthreads();

    // phase C: pack records into the bin's contiguous bucket region
    for (int slot = t; slot < nslots; slot += 1024) {
        int cell = slot >> 6;
        int j    = slot & (CAPBB - 1);
        if (j < cellc[cell]) {
            uint2 r = binned[((size_t)cell * nbins + b) * CAPBB + j];
            int l = (int)r.y;
            int p = atomicAdd(&rk2[l], 1);
            bucket[G + (off2[l] - cnt2[l]) + p] = r.x;
        }
    }

    if (b == 0) {
        if (t < KB && spill_cnt[t] > 0) atomicAdd(&stot, spill_cnt[t]);
        __syncthreads();
        if (t == 0) *spill_total = stot;
    }
}

// ---------------------------------------------------------------------------
// K3: gather. 16 lanes/node, half8 (16 B) per lane — one load covers the
// lane's 8 cols; 8/4/1 unrolled record loop; nontemporal f32x4 stores.
// ---------------------------------------------------------------------------
__global__ __launch_bounds__(NT)
void gather_kernel(const _Float16* __restrict__ emb,
                   const uint2* __restrict__ offdeg,
                   const unsigned int* __restrict__ bucket,
                   const int* __restrict__ spill_total,
                   const int* __restrict__ spill_cnt,
                   const uint2* __restrict__ spill,
                   float* __restrict__ out, int n_nodes, int per_block) {
    int tid = blockIdx.x * NT + threadIdx.x;
    int node = tid >> 4;
    if (node >= n_nodes) return;
    int col = (tid & 15) * 8;

    uint2 od = offdeg[node];
    int beg = (int)od.x;
    int end = beg + (int)od.y;
    float a0=0.f,a1=0.f,a2=0.f,a3=0.f,a4=0.f,a5=0.f,a6=0.f,a7=0.f;

    const _Float16* ebase = emb + col;

#define ACC8(h, m)                                                             \
    a0 += (float)(h)[0]*(m); a1 += (float)(h)[1]*(m);                          \
    a2 += (float)(h)[2]*(m); a3 += (float)(h)[3]*(m);                          \
    a4 += (float)(h)[4]*(m); a5 += (float)(h)[5]*(m);                          \
    a6 += (float)(h)[6]*(m); a7 += (float)(h)[7]*(m);

    int i = beg;
    for (; i + 8 <= end; i += 8) {
        unsigned int r0 = bucket[i+0], r1 = bucket[i+1], r2 = bucket[i+2], r3 = bucket[i+3];
        unsigned int r4 = bucket[i+4], r5 = bucket[i+5], r6 = bucket[i+6], r7 = bucket[i+7];
        half8 h0 = *reinterpret_cast<const half8*>(ebase + (size_t)(r0 & 0x7FFFFFFFu) * D);
        half8 h1 = *reinterpret_cast<const half8*>(ebase + (size_t)(r1 & 0x7FFFFFFFu) * D);
        half8 h2 = *reinterpret_cast<const half8*>(ebase + (size_t)(r2 & 0x7FFFFFFFu) * D);
        half8 h3 = *reinterpret_cast<const half8*>(ebase + (size_t)(r3 & 0x7FFFFFFFu) * D);
        half8 h4 = *reinterpret_cast<const half8*>(ebase + (size_t)(r4 & 0x7FFFFFFFu) * D);
        half8 h5 = *reinterpret_cast<const half8*>(ebase + (size_t)(r5 & 0x7FFFFFFFu) * D);
        half8 h6 = *reinterpret_cast<const half8*>(ebase + (size_t)(r6 & 0x7FFFFFFFu) * D);
        half8 h7 = *reinterpret_cast<const half8*>(ebase + (size_t)(r7 & 0x7FFFFFFFu) * D);
        float m0 = (r0 >> 31) ? 2.f : 1.f, m1 = (r1 >> 31) ? 2.f : 1.f;
        float m2 = (r2 >> 31) ? 2.f : 1.f, m3 = (r3 >> 31) ? 2.f : 1.f;
        float m4 = (r4 >> 31) ? 2.f : 1.f, m5 = (r5 >> 31) ? 2.f : 1.f;
        float m6 = (r6 >> 31) ? 2.f : 1.f, m7 = (r7 >> 31) ? 2.f : 1.f;
        ACC8(h0, m0) ACC8(h1, m1) ACC8(h2, m2) ACC8(h3, m3)
        ACC8(h4, m4) ACC8(h5, m5) ACC8(h6, m6) ACC8(h7, m7)
    }
    for (; i + 4 <= end; i += 4) {
        unsigned int r0 = bucket[i+0], r1 = bucket[i+1], r2 = bucket[i+2], r3 = bucket[i+3];
        half8 h0 = *reinterpret_cast<const half8*>(ebase + (size_t)(r0 & 0x7FFFFFFFu) * D);
        half8 h1 = *reinterpret_cast<const half8*>(ebase + (size_t)(r1 & 0x7FFFFFFFu) * D);
        half8 h2 = *reinterpret_cast<const half8*>(ebase + (size_t)(r2 & 0x7FFFFFFFu) * D);
        half8 h3 = *reinterpret_cast<const half8*>(ebase + (size_t)(r3 & 0x7FFFFFFFu) * D);
        float m0 = (r0 >> 31) ? 2.f : 1.f, m1 = (r1 >> 31) ? 2.f : 1.f;
        float m2 = (r2 >> 31) ? 2.f : 1.f, m3 = (r3 >> 31) ? 2.f : 1.f;
        ACC8(h0, m0) ACC8(h1, m1) ACC8(h2, m2) ACC8(h3, m3)
    }
    for (; i < end; ++i) {
        unsigned int r = bucket[i];
        half8 h = *reinterpret_cast<const half8*>(ebase + (size_t)(r & 0x7FFFFFFFu) * D);
        float m = (r >> 31) ? 2.f : 1.f;
        ACC8(h, m)
    }

    // Spill guard (expected zero; slow-but-correct for adversarial input)
    if (*spill_total > 0) {
        for (int blk = 0; blk < KB; ++blk) {
            int sc = spill_cnt[blk];
            for (int j = 0; j < sc; ++j) {
                uint2 o = spill[(size_t)blk * per_block + j];
                if ((int)o.y == node) {
                    half8 h = *reinterpret_cast<const half8*>(ebase + (size_t)(o.x & 0x7FFFFFFFu) * D);
                    float m = (o.x >> 31) ? 2.f : 1.f;
                    ACC8(h, m)
                }
            }
        }
    }
#undef ACC8

    float* obase = out + (size_t)node * D + col;
    f32x4 lo, hi;
    lo.x = a0; lo.y = a1; lo.z = a2; lo.w = a3;
    hi.x = a4; hi.y = a5; hi.z = a6; hi.w = a7;
    __builtin_nontemporal_store(lo, reinterpret_cast<f32x4*>(obase));
    __builtin_nontemporal_store(hi, reinterpret_cast<f32x4*>(obase + 4));
}

// ---------------------------------------------------------------------------
// Fallback: atomic scatter.
// ---------------------------------------------------------------------------
__global__ void edge_scatter_fallback(const float* __restrict__ ge,
                                      const float* __restrict__ weight,
                                      const int* __restrict__ e_feat,
                                      const int* __restrict__ src,
                                      const int* __restrict__ dst,
                                      float* __restrict__ out, int n_edges) {
    long long tid = (long long)blockIdx.x * blockDim.x + threadIdx.x;
    int edge = (int)(tid >> 5);
    if (edge >= n_edges) return;
    int col = (int)(tid & 31) * 4;
    int e = e_feat[edge];
    float mult = (e == 0 || e == 6 || e == 14 || e == 30) ? 2.0f : 1.0f;
    float4 w = *reinterpret_cast<const float4*>(weight + col);
    float4 g = *reinterpret_cast<const float4*>(ge + (long long)src[edge] * D + col);
    float4 v = elu_mul(g, w);
    float* o = out + (long long)dst[edge] * D + col;
    atomicAdd(o + 0, v.x * mult);
    atomicAdd(o + 1, v.y * mult);
    atomicAdd(o + 2, v.z * mult);
    atomicAdd(o + 3, v.w * mult);
}

extern "C" void kernel_launch(void* const* d_in, const int* in_sizes, int n_in,
                              void* d_out, int out_size, void* d_ws, size_t ws_size,
                              hipStream_t stream) {
    const float* ge     = (const float*)d_in[0];   // [N, 128]
    const float* weight = (const float*)d_in[1];   // [1, 128]
    const int*   e_feat = (const int*)d_in[2];     // [E]
    const int*   src    = (const int*)d_in[3];     // [E]
    const int*   dst    = (const int*)d_in[4];     // [E]
    float* out = (float*)d_out;                    // [N, 128]

    int n_edges = in_sizes[2];
    int n_nodes = out_size / D;
    int nbins   = (n_nodes + 255) >> 8;            // 196 for N=50000
    int per_block = (n_edges + KB - 1) / KB;       // 2000 for E=640000
    int capb_out  = KB * CAPBB;                    // 20480 records per bin region

    auto align256 = [](size_t x) { return (x + 255) & ~(size_t)255; };
    size_t o_emb    = 0;
    size_t o_binned = o_emb    + align256((size_t)n_nodes * D * sizeof(_Float16));
    size_t o_spill  = o_binned + align256((size_t)KB * nbins * CAPBB * 8);
    size_t o_cnts   = o_spill  + align256((size_t)KB * per_block * 8);
    size_t o_scnt   = o_cnts   + align256((size_t)KB * nbins * 4);
    size_t o_stot   = o_scnt   + align256((size_t)KB * 4);
    size_t o_offdeg = o_stot   + 256;
    size_t o_bucket = o_offdeg + align256((size_t)n_nodes * 8);
    size_t need     = o_bucket + align256((size_t)nbins * capb_out * 4);

    if (ws_size < need || nbins > NBMAX) {
        (void)hipMemsetAsync(d_out, 0, (size_t)out_size * sizeof(float), stream);
        long long total = (long long)n_edges * 32;
        edge_scatter_fallback<<<(int)((total + 255) / 256), 256, 0, stream>>>(
            ge, weight, e_feat, src, dst, out, n_edges);
        return;
    }

    char* ws = (char*)d_ws;
    _Float16*     emb     = (_Float16*)(ws + o_emb);
    uint2*        binned  = (uint2*)(ws + o_binned);
    uint2*        spill   = (uint2*)(ws + o_spill);
    int*          cnts    = (int*)(ws + o_cnts);
    int*          scnt    = (int*)(ws + o_scnt);
    int*          stot    = (int*)(ws + o_stot);
    uint2*        offdeg  = (uint2*)(ws + o_offdeg);
    unsigned int* bucket  = (unsigned int*)(ws + o_bucket);

    int quads = n_nodes * (D / 4);
    int embBlocks = (quads + NT - 1) / NT;

    fused_kernel<<<KB + embBlocks, NT, 0, stream>>>(
        ge, weight, e_feat, src, dst, emb, binned, cnts, spill, scnt,
        n_nodes, n_edges, nbins, per_block);
    csr_kernel<<<nbins, 1024, 0, stream>>>(binned, cnts, offdeg, bucket,
                                           scnt, stot, n_nodes, nbins, capb_out);

    long long total = (long long)n_nodes * 16;
    gather_kernel<<<(int)((total + NT - 1) / NT), NT, 0, stream>>>(
        emb, offdeg, bucket, stot, scnt, spill, out, n_nodes, per_block);
}

// Round 18
// 57.092 us; speedup vs baseline: 1.0736x; 1.0736x over previous
//
#include <hip/hip_runtime.h>

#define D      128
#define NT     256
#define KB     320       // bin blocks (edge partition)
#define CAPBB  64        // records per (block,bin) cell
#define NBMAX  256       // max bins => n_nodes <= 65536

typedef __attribute__((ext_vector_type(4))) _Float16 half4;
typedef __attribute__((ext_vector_type(4))) float    f32x4;

__device__ __forceinline__ float4 elu_mul(float4 g, float4 w) {
    float4 v;
    v.x = g.x * w.x; v.y = g.y * w.y; v.z = g.z * w.z; v.w = g.w * w.w;
    v.x = (v.x > 0.0f) ? v.x : (__expf(v.x) - 1.0f);
    v.y = (v.y > 0.0f) ? v.y : (__expf(v.y) - 1.0f);
    v.z = (v.z > 0.0f) ? v.z : (__expf(v.z) - 1.0f);
    v.w = (v.w > 0.0f) ? v.w : (__expf(v.w) - 1.0f);
    return v;
}

// ---------------------------------------------------------------------------
// K1 (fused): blocks [0,KB): deterministic binning into private (blk,bin)
// cells — LDS rank only, NO global atomics, NO init needed. Blocks [KB,...):
// emb = elu(ge*w) fp16.
// ---------------------------------------------------------------------------
__global__ __launch_bounds__(NT)
void fused_kernel(const float* __restrict__ ge, const float* __restrict__ weight,
                  const int* __restrict__ e_feat, const int* __restrict__ src,
                  const int* __restrict__ dst,
                  _Float16* __restrict__ emb, uint2* __restrict__ binned,
                  int* __restrict__ cnts, uint2* __restrict__ spill,
                  int* __restrict__ spill_cnt,
                  int n_nodes, int n_edges, int nbins, int per_block) {
    if ((int)blockIdx.x < KB) {
        __shared__ int rk[NBMAX];
        __shared__ int sp;
        int t = threadIdx.x;
        for (int i = t; i < NBMAX; i += NT) rk[i] = 0;
        if (t == 0) sp = 0;
        __syncthreads();

        int blk = blockIdx.x;
        int e0 = blk * per_block;
        int e1 = e0 + per_block; if (e1 > n_edges) e1 = n_edges;
        for (int e = e0 + t; e < e1; e += NT) {
            int d = dst[e];
            int b = d >> 8;
            int f = e_feat[e];
            unsigned int flag = (f == 0 || f == 6 || f == 14 || f == 30) ? 1u : 0u;
            unsigned int rec  = (unsigned int)src[e] | (flag << 31);
            int r = atomicAdd(&rk[b], 1);
            if (r < CAPBB) {
                binned[((size_t)blk * nbins + b) * CAPBB + r] =
                    make_uint2(rec, (unsigned int)(d & 255));
            } else {
                int s = atomicAdd(&sp, 1);
                spill[(size_t)blk * per_block + s] = make_uint2(rec, (unsigned int)d);
            }
        }
        __syncthreads();
        for (int b = t; b < nbins; b += NT)
            cnts[blk * nbins + b] = rk[b] < CAPBB ? rk[b] : CAPBB;
        if (t == 0) spill_cnt[blk] = sp;
    } else {
        int t = ((int)blockIdx.x - KB) * NT + threadIdx.x;
        int quads = n_nodes * (D / 4);
        if (t < quads) {
            int col = (t & 31) * 4;
            float4 g = *reinterpret_cast<const float4*>(ge + (size_t)t * 4);
            float4 w = *reinterpret_cast<const float4*>(weight + col);
            float4 v = elu_mul(g, w);
            half4 h;
            h.x = (_Float16)v.x; h.y = (_Float16)v.y;
            h.z = (_Float16)v.z; h.w = (_Float16)v.w;
            *reinterpret_cast<half4*>(emb + (size_t)t * 4) = h;
        }
    }
}

// ---------------------------------------------------------------------------
// K2: per-bin CSR pack. One 1024-thread block per bin; threads 0..KB own one
// cell each (cell-sequential reads). Node histogram + LDS scan -> offdeg;
// pack records into the bin's static contiguous bucket region.
// ---------------------------------------------------------------------------
__global__ __launch_bounds__(1024)
void csr_kernel(const uint2* __restrict__ binned, const int* __restrict__ cnts,
                uint2* __restrict__ offdeg, unsigned int* __restrict__ bucket,
                const int* __restrict__ spill_cnt, int* __restrict__ spill_total,
                int n_nodes, int nbins, int capb_out) {
    __shared__ int cnt2[NBMAX];
    __shared__ int off2[NBMAX];
    __shared__ int rk2[NBMAX];
    __shared__ int cellc[KB];
    __shared__ int stot;
    int t = threadIdx.x;
    int b = blockIdx.x;

    for (int i = t; i < NBMAX; i += 1024) { cnt2[i] = 0; rk2[i] = 0; }
    if (t < KB) cellc[t] = cnts[t * nbins + b];
    if (t == 0) stot = 0;
    __syncthreads();

    // phase A: node-local histogram over dst&255
    if (t < KB) {
        const uint2* cell = binned + ((size_t)t * nbins + b) * CAPBB;
        int c = cellc[t];
        for (int j = 0; j < c; ++j) atomicAdd(&cnt2[cell[j].y], 1);
    }
    __syncthreads();

    // inclusive scan over 256 node slots
    if (t < NBMAX) off2[t] = cnt2[t];
    __syncthreads();
    for (int d2 = 1; d2 < NBMAX; d2 <<= 1) {
        int x = 0;
        if (t < NBMAX && t >= d2) x = off2[t - d2];
        __syncthreads();
        if (t < NBMAX) off2[t] += x;
        __syncthreads();
    }

    int G = b * capb_out;
    if (t < NBMAX) {
        int node = (b << 8) + t;
        if (node < n_nodes)
            offdeg[node] = make_uint2((unsigned int)(G + off2[t] - cnt2[t]),
                                      (unsigned int)cnt2[t]);
    }
    __syncthreads();

    // phase C: pack records (grouped by node) into contiguous region
    if (t < KB) {
        const uint2* cell = binned + ((size_t)t * nbins + b) * CAPBB;
        int c = cellc[t];
        for (int j = 0; j < c; ++j) {
            uint2 r = cell[j];
            int l = (int)r.y;
            int p = atomicAdd(&rk2[l], 1);
            bucket[G + (off2[l] - cnt2[l]) + p] = r.x;
        }
    }

    if (b == 0) {
        if (t < KB && spill_cnt[t] > 0) atomicAdd(&stot, spill_cnt[t]);
        __syncthreads();
        if (t == 0) *spill_total = stot;
    }
}

// ---------------------------------------------------------------------------
// K3: gather. 32 lanes/node, 4 fp16 cols/lane; one uint2 offdeg broadcast
// load; 8/4/1 unrolled record loop; nontemporal output store.
// ---------------------------------------------------------------------------
__global__ __launch_bounds__(NT)
void gather_kernel(const _Float16* __restrict__ emb,
                   const uint2* __restrict__ offdeg,
                   const unsigned int* __restrict__ bucket,
                   const int* __restrict__ spill_total,
                   const int* __restrict__ spill_cnt,
                   const uint2* __restrict__ spill,
                   float* __restrict__ out, int n_nodes, int per_block) {
    int tid = blockIdx.x * NT + threadIdx.x;
    int node = tid >> 5;
    if (node >= n_nodes) return;
    int col = (tid & 31) * 4;

    uint2 od = offdeg[node];
    int beg = (int)od.x;
    int end = beg + (int)od.y;
    float4 acc = make_float4(0.f, 0.f, 0.f, 0.f);

    int i = beg;
    for (; i + 8 <= end; i += 8) {
        unsigned int r0 = bucket[i+0], r1 = bucket[i+1], r2 = bucket[i+2], r3 = bucket[i+3];
        unsigned int r4 = bucket[i+4], r5 = bucket[i+5], r6 = bucket[i+6], r7 = bucket[i+7];
        half4 h0 = *reinterpret_cast<const half4*>(emb + (size_t)(r0 & 0x7FFFFFFFu) * D + col);
        half4 h1 = *reinterpret_cast<const half4*>(emb + (size_t)(r1 & 0x7FFFFFFFu) * D + col);
        half4 h2 = *reinterpret_cast<const half4*>(emb + (size_t)(r2 & 0x7FFFFFFFu) * D + col);
        half4 h3 = *reinterpret_cast<const half4*>(emb + (size_t)(r3 & 0x7FFFFFFFu) * D + col);
        half4 h4 = *reinterpret_cast<const half4*>(emb + (size_t)(r4 & 0x7FFFFFFFu) * D + col);
        half4 h5 = *reinterpret_cast<const half4*>(emb + (size_t)(r5 & 0x7FFFFFFFu) * D + col);
        half4 h6 = *reinterpret_cast<const half4*>(emb + (size_t)(r6 & 0x7FFFFFFFu) * D + col);
        half4 h7 = *reinterpret_cast<const half4*>(emb + (size_t)(r7 & 0x7FFFFFFFu) * D + col);
        float m0 = (r0 >> 31) ? 2.f : 1.f, m1 = (r1 >> 31) ? 2.f : 1.f;
        float m2 = (r2 >> 31) ? 2.f : 1.f, m3 = (r3 >> 31) ? 2.f : 1.f;
        float m4 = (r4 >> 31) ? 2.f : 1.f, m5 = (r5 >> 31) ? 2.f : 1.f;
        float m6 = (r6 >> 31) ? 2.f : 1.f, m7 = (r7 >> 31) ? 2.f : 1.f;
        acc.x += (float)h0.x*m0 + (float)h1.x*m1 + (float)h2.x*m2 + (float)h3.x*m3
               + (float)h4.x*m4 + (float)h5.x*m5 + (float)h6.x*m6 + (float)h7.x*m7;
        acc.y += (float)h0.y*m0 + (float)h1.y*m1 + (float)h2.y*m2 + (float)h3.y*m3
               + (float)h4.y*m4 + (float)h5.y*m5 + (float)h6.y*m6 + (float)h7.y*m7;
        acc.z += (float)h0.z*m0 + (float)h1.z*m1 + (float)h2.z*m2 + (float)h3.z*m3
               + (float)h4.z*m4 + (float)h5.z*m5 + (float)h6.z*m6 + (float)h7.z*m7;
        acc.w += (float)h0.w*m0 + (float)h1.w*m1 + (float)h2.w*m2 + (float)h3.w*m3
               + (float)h4.w*m4 + (float)h5.w*m5 + (float)h6.w*m6 + (float)h7.w*m7;
    }
    for (; i + 4 <= end; i += 4) {
        unsigned int r0 = bucket[i+0], r1 = bucket[i+1], r2 = bucket[i+2], r3 = bucket[i+3];
        half4 h0 = *reinterpret_cast<const half4*>(emb + (size_t)(r0 & 0x7FFFFFFFu) * D + col);
        half4 h1 = *reinterpret_cast<const half4*>(emb + (size_t)(r1 & 0x7FFFFFFFu) * D + col);
        half4 h2 = *reinterpret_cast<const half4*>(emb + (size_t)(r2 & 0x7FFFFFFFu) * D + col);
        half4 h3 = *reinterpret_cast<const half4*>(emb + (size_t)(r3 & 0x7FFFFFFFu) * D + col);
        float m0 = (r0 >> 31) ? 2.f : 1.f, m1 = (r1 >> 31) ? 2.f : 1.f;
        float m2 = (r2 >> 31) ? 2.f : 1.f, m3 = (r3 >> 31) ? 2.f : 1.f;
        acc.x += (float)h0.x*m0 + (float)h1.x*m1 + (float)h2.x*m2 + (float)h3.x*m3;
        acc.y += (float)h0.y*m0 + (float)h1.y*m1 + (float)h2.y*m2 + (float)h3.y*m3;
        acc.z += (float)h0.z*m0 + (float)h1.z*m1 + (float)h2.z*m2 + (float)h3.z*m3;
        acc.w += (float)h0.w*m0 + (float)h1.w*m1 + (float)h2.w*m2 + (float)h3.w*m3;
    }
    for (; i < end; ++i) {
        unsigned int r = bucket[i];
        half4 h = *reinterpret_cast<const half4*>(emb + (size_t)(r & 0x7FFFFFFFu) * D + col);
        float m = (r >> 31) ? 2.f : 1.f;
        acc.x += (float)h.x*m; acc.y += (float)h.y*m;
        acc.z += (float)h.z*m; acc.w += (float)h.w*m;
    }

    // Spill guard (expected zero; slow-but-correct path for adversarial input)
    if (*spill_total > 0) {
        for (int blk = 0; blk < KB; ++blk) {
            int sc = spill_cnt[blk];
            for (int j = 0; j < sc; ++j) {
                uint2 o = spill[(size_t)blk * per_block + j];
                if ((int)o.y == node) {
                    half4 h = *reinterpret_cast<const half4*>(emb + (size_t)(o.x & 0x7FFFFFFFu) * D + col);
                    float m = (o.x >> 31) ? 2.f : 1.f;
                    acc.x += (float)h.x*m; acc.y += (float)h.y*m;
                    acc.z += (float)h.z*m; acc.w += (float)h.w*m;
                }
            }
        }
    }

    f32x4 o;
    o.x = acc.x; o.y = acc.y; o.z = acc.z; o.w = acc.w;
    __builtin_nontemporal_store(o, reinterpret_cast<f32x4*>(out + (size_t)node * D + col));
}

// ---------------------------------------------------------------------------
// Fallback: atomic scatter.
// ---------------------------------------------------------------------------
__global__ void edge_scatter_fallback(const float* __restrict__ ge,
                                      const float* __restrict__ weight,
                                      const int* __restrict__ e_feat,
                                      const int* __restrict__ src,
                                      const int* __restrict__ dst,
                                      float* __restrict__ out, int n_edges) {
    long long tid = (long long)blockIdx.x * blockDim.x + threadIdx.x;
    int edge = (int)(tid >> 5);
    if (edge >= n_edges) return;
    int col = (int)(tid & 31) * 4;
    int e = e_feat[edge];
    float mult = (e == 0 || e == 6 || e == 14 || e == 30) ? 2.0f : 1.0f;
    float4 w = *reinterpret_cast<const float4*>(weight + col);
    float4 g = *reinterpret_cast<const float4*>(ge + (long long)src[edge] * D + col);
    float4 v = elu_mul(g, w);
    float* o = out + (long long)dst[edge] * D + col;
    atomicAdd(o + 0, v.x * mult);
    atomicAdd(o + 1, v.y * mult);
    atomicAdd(o + 2, v.z * mult);
    atomicAdd(o + 3, v.w * mult);
}

extern "C" void kernel_launch(void* const* d_in, const int* in_sizes, int n_in,
                              void* d_out, int out_size, void* d_ws, size_t ws_size,
                              hipStream_t stream) {
    const float* ge     = (const float*)d_in[0];   // [N, 128]
    const float* weight = (const float*)d_in[1];   // [1, 128]
    const int*   e_feat = (const int*)d_in[2];     // [E]
    const int*   src    = (const int*)d_in[3];     // [E]
    const int*   dst    = (const int*)d_in[4];     // [E]
    float* out = (float*)d_out;                    // [N, 128]

    int n_edges = in_sizes[2];
    int n_nodes = out_size / D;
    int nbins   = (n_nodes + 255) >> 8;            // 196 for N=50000
    int per_block = (n_edges + KB - 1) / KB;       // 2000 for E=640000
    int capb_out  = KB * CAPBB;                    // 20480 records per bin region

    auto align256 = [](size_t x) { return (x + 255) & ~(size_t)255; };
    size_t o_emb    = 0;
    size_t o_binned = o_emb    + align256((size_t)n_nodes * D * sizeof(_Float16));
    size_t o_spill  = o_binned + align256((size_t)KB * nbins * CAPBB * 8);
    size_t o_cnts   = o_spill  + align256((size_t)KB * per_block * 8);
    size_t o_scnt   = o_cnts   + align256((size_t)KB * nbins * 4);
    size_t o_stot   = o_scnt   + align256((size_t)KB * 4);
    size_t o_offdeg = o_stot   + 256;
    size_t o_bucket = o_offdeg + align256((size_t)n_nodes * 8);
    size_t need     = o_bucket + align256((size_t)nbins * capb_out * 4);

    if (ws_size < need || nbins > NBMAX) {
        (void)hipMemsetAsync(d_out, 0, (size_t)out_size * sizeof(float), stream);
        long long total = (long long)n_edges * 32;
        edge_scatter_fallback<<<(int)((total + 255) / 256), 256, 0, stream>>>(
            ge, weight, e_feat, src, dst, out, n_edges);
        return;
    }

    char* ws = (char*)d_ws;
    _Float16*     emb     = (_Float16*)(ws + o_emb);
    uint2*        binned  = (uint2*)(ws + o_binned);
    uint2*        spill   = (uint2*)(ws + o_spill);
    int*          cnts    = (int*)(ws + o_cnts);
    int*          scnt    = (int*)(ws + o_scnt);
    int*          stot    = (int*)(ws + o_stot);
    uint2*        offdeg  = (uint2*)(ws + o_offdeg);
    unsigned int* bucket  = (unsigned int*)(ws + o_bucket);

    int quads = n_nodes * (D / 4);
    int embBlocks = (quads + NT - 1) / NT;

    fused_kernel<<<KB + embBlocks, NT, 0, stream>>>(
        ge, weight, e_feat, src, dst, emb, binned, cnts, spill, scnt,
        n_nodes, n_edges, nbins, per_block);
    csr_kernel<<<nbins, 1024, 0, stream>>>(binned, cnts, offdeg, bucket,
                                           scnt, stot, n_nodes, nbins, capb_out);

    long long total = (long long)n_nodes * 32;
    gather_kernel<<<(int)((total + 255) / 256), NT, 0, stream>>>(
        emb, offdeg, bucket, stot, scnt, spill, out, n_nodes, per_block);
}